// Round 11
// baseline (2246.616 us; speedup 1.0000x reference)
//
#include <hip/hip_runtime.h>
#include <math.h>

#define DT    0.01f
#define B_    64
#define S_    4096
#define I_    128
#define H_    256
#define O_    128

typedef _Float16 f16x8  __attribute__((ext_vector_type(8)));
typedef _Float16 half2v __attribute__((ext_vector_type(2)));
typedef float    f32x4  __attribute__((ext_vector_type(4)));

#if defined(__has_builtin)
#if __has_builtin(__builtin_amdgcn_fdot2)
#define FDOT2(a, b, c) __builtin_amdgcn_fdot2((a), (b), (c), false)
#endif
#endif
#ifndef FDOT2
#define FDOT2(a, b, c) \
  fmaf((float)(a).x, (float)(b).x, fmaf((float)(a).y, (float)(b).y, (c)))
#endif

static __device__ __forceinline__ half2v mkh2(_Float16 a, _Float16 b) {
  half2v r; r.x = a; r.y = b; return r;
}

// ---------------------------------------------------------------------------
// Kernel 1: xproj[b,t,j] = b[j] + sum_i x[b,t,i] * W[i,j]   (W rows 0..127)
// ---------------------------------------------------------------------------
#define RPB 64

__global__ __launch_bounds__(256, 2) void xproj_kernel(
    const float* __restrict__ x, const float* __restrict__ W,
    const float* __restrict__ bias, float* __restrict__ xp)
{
  __shared__ __align__(16) float xs[RPB][I_];
  const int j = threadIdx.x;

  float w[I_];
#pragma unroll
  for (int k = 0; k < I_; ++k) w[k] = W[k * H_ + j];
  const float bj = bias[j];

  const size_t row0 = (size_t)blockIdx.x * RPB;

  const float4* src4 = (const float4*)(x + row0 * I_);
  float4* xs4 = (float4*)&xs[0][0];
#pragma unroll
  for (int i = 0; i < (RPB * I_ / 4) / 256; ++i)
    xs4[j + i * 256] = src4[j + i * 256];
  __syncthreads();

  for (int r = 0; r < RPB; r += 4) {
    float a0 = bj, a1 = bj, a2 = bj, a3 = bj;
    const float4* r0 = (const float4*)xs[r + 0];
    const float4* r1 = (const float4*)xs[r + 1];
    const float4* r2 = (const float4*)xs[r + 2];
    const float4* r3 = (const float4*)xs[r + 3];
#pragma unroll
    for (int k4 = 0; k4 < I_ / 4; ++k4) {
      float4 v0 = r0[k4], v1 = r1[k4], v2 = r2[k4], v3 = r3[k4];
      a0 = fmaf(v0.x, w[4*k4+0], a0); a0 = fmaf(v0.y, w[4*k4+1], a0);
      a0 = fmaf(v0.z, w[4*k4+2], a0); a0 = fmaf(v0.w, w[4*k4+3], a0);
      a1 = fmaf(v1.x, w[4*k4+0], a1); a1 = fmaf(v1.y, w[4*k4+1], a1);
      a1 = fmaf(v1.z, w[4*k4+2], a1); a1 = fmaf(v1.w, w[4*k4+3], a1);
      a2 = fmaf(v2.x, w[4*k4+0], a2); a2 = fmaf(v2.y, w[4*k4+1], a2);
      a2 = fmaf(v2.z, w[4*k4+2], a2); a2 = fmaf(v2.w, w[4*k4+3], a2);
      a3 = fmaf(v3.x, w[4*k4+0], a3); a3 = fmaf(v3.y, w[4*k4+1], a3);
      a3 = fmaf(v3.z, w[4*k4+2], a3); a3 = fmaf(v3.w, w[4*k4+3], a3);
    }
    xp[(row0 + r + 0) * H_ + j] = a0;
    xp[(row0 + r + 1) * H_ + j] = a1;
    xp[(row0 + r + 2) * H_ + j] = a2;
    xp[(row0 + r + 3) * H_ + j] = a3;
  }
}

// ---------------------------------------------------------------------------
// Kernel 2: LTC recurrence, hybrid MFMA+VALU, 512 threads = 8 waves (2/SIMD).
// r10 proved the all-MFMA mapping is throughput-saturated (16cy/MFMA = µbench
// ceiling; 32 tiles/SIMD = 512cy hard floor) -> move half of K to the VALU.
// Every piece below ran in a PASSING kernel:
//  - MFMA part (r6 verbatim, kt<4): K[0,128), 2 col-groups x 4 K-tiles =
//    8 MFMA/wave -> 16/SIMD = 256cy pipe. C-in seeded with xpre.
//  - dot2 part (r8 verbatim): K[128,256): lane l reads its gg-half
//    hs[128+gg*64 ..+64) as 8 broadcast ds_read_b128 (gg=(l>>4)&1), does
//    32 fdot2 vs its own column o's weights; lanes (l, l^16) share o and
//    hold opposite halves -> ONE ds_swizzle xor-16 (0x401F) completes the
//    256-term sum. No xor-32 anywhere (r9's unproven primitive).
//  - update algebra (r10 verbatim): h' = (E*p+q)/(E*rc+sc), p/q off-path.
// Mapping: o = wv*32 + (l>>5)*16 + (l&15); writer = gg==0 lane of each pair.
// ONE __syncthreads per step.
// ---------------------------------------------------------------------------
__global__ __launch_bounds__(512, 2) void ltc_main(
    const float* __restrict__ xp, const float* __restrict__ W,
    const float* __restrict__ tau, const float* __restrict__ A,
    const float* __restrict__ Wo, const float* __restrict__ bo,
    float* __restrict__ out)
{
  const int b  = blockIdx.x;
  const int t  = threadIdx.x;
  const int wv = t >> 6;       // 0..7
  const int l  = t & 63;
  const int g  = l >> 4;       // k-slice group 0..3 (MFMA A-frag slice)
  const int gg = g & 1;        // which 64-half of the dot2 K-range
  const int c  = l & 15;       // col within 16-group
  const int s  = l >> 5;       // col-group select
  const int o  = wv * 32 + s * 16 + c;  // this lane's output (2 lanes/output)

  // MFMA B-fragments for K in [0,128): 2 col-groups x 4 K-tiles (32 VGPR)
  f16x8 bw[2][4];
#pragma unroll
  for (int sg = 0; sg < 2; ++sg)
#pragma unroll
    for (int kt = 0; kt < 4; ++kt)
#pragma unroll
      for (int j = 0; j < 8; ++j)
        bw[sg][kt][j] =
            (_Float16)W[(I_ + kt * 32 + g * 8 + j) * H_ + (wv * 32 + sg * 16 + c)];

  // dot2 weights for K in [128+gg*64, 128+gg*64+64), own column o (32 VGPR)
  half2v wdd[32];
#pragma unroll
  for (int i = 0; i < 32; ++i) {
    const int k = I_ + 128 + gg * 64 + 2 * i;
    wdd[i].x = (_Float16)W[k * H_ + o];
    wdd[i].y = (_Float16)W[(k + 1) * H_ + o];
  }

  __shared__ __align__(16) _Float16 hs[2][H_];
  __shared__ float hfin[H_];

  const float dtA  = DT * A[o];
  const float base = 1.0f + DT * (1.0f / tau[o]);
  const float rc   = base + DT;
  const float sc   = base - DT;

  const float* xprow = xp + (size_t)b * S_ * H_ + o;

  float h = 0.0f, p = dtA, q = -dtA;
  float xpre = xprow[0];
  if (t < H_) hs[0][t] = (_Float16)0.0f;
  __syncthreads();

#define DOT8(HV, W0, W1, W2, W3)                                             \
  dv0 = FDOT2(mkh2(HV[0], HV[1]), W0, dv0);                                  \
  dv1 = FDOT2(mkh2(HV[2], HV[3]), W1, dv1);                                  \
  dv0 = FDOT2(mkh2(HV[4], HV[5]), W2, dv0);                                  \
  dv1 = FDOT2(mkh2(HV[6], HV[7]), W3, dv1);

#define LTC_BODY(RB, WB, STEP)                                               \
  {                                                                          \
    const _Float16* hb = &hs[RB][g * 8];                                     \
    const int snext = ((STEP) + 1 < S_) ? (STEP) + 1 : (STEP);               \
    const float xnext = xprow[(size_t)snext * H_];                           \
    f16x8 a0_ = *(const f16x8*)(hb);                                         \
    f16x8 a1_ = *(const f16x8*)(hb + 32);                                    \
    f16x8 a2_ = *(const f16x8*)(hb + 64);                                    \
    f16x8 a3_ = *(const f16x8*)(hb + 96);                                    \
    const f16x8* h2p = (const f16x8*)&hs[RB][128 + gg * 64];                 \
    f16x8 hv0 = h2p[0], hv1 = h2p[1], hv2 = h2p[2], hv3 = h2p[3];            \
    f16x8 hv4 = h2p[4], hv5 = h2p[5], hv6 = h2p[6], hv7 = h2p[7];            \
    f32x4 ac0 = {xpre, xpre, xpre, xpre};                                    \
    f32x4 ac1 = {xpre, xpre, xpre, xpre};                                    \
    ac0 = __builtin_amdgcn_mfma_f32_16x16x32_f16(a0_, bw[0][0], ac0, 0,0,0); \
    ac1 = __builtin_amdgcn_mfma_f32_16x16x32_f16(a0_, bw[1][0], ac1, 0,0,0); \
    ac0 = __builtin_amdgcn_mfma_f32_16x16x32_f16(a1_, bw[0][1], ac0, 0,0,0); \
    ac1 = __builtin_amdgcn_mfma_f32_16x16x32_f16(a1_, bw[1][1], ac1, 0,0,0); \
    ac0 = __builtin_amdgcn_mfma_f32_16x16x32_f16(a2_, bw[0][2], ac0, 0,0,0); \
    ac1 = __builtin_amdgcn_mfma_f32_16x16x32_f16(a2_, bw[1][2], ac1, 0,0,0); \
    ac0 = __builtin_amdgcn_mfma_f32_16x16x32_f16(a3_, bw[0][3], ac0, 0,0,0); \
    ac1 = __builtin_amdgcn_mfma_f32_16x16x32_f16(a3_, bw[1][3], ac1, 0,0,0); \
    float dv0 = 0.f, dv1 = 0.f;                                              \
    DOT8(hv0, wdd[0],  wdd[1],  wdd[2],  wdd[3])                             \
    DOT8(hv1, wdd[4],  wdd[5],  wdd[6],  wdd[7])                             \
    DOT8(hv2, wdd[8],  wdd[9],  wdd[10], wdd[11])                            \
    DOT8(hv3, wdd[12], wdd[13], wdd[14], wdd[15])                            \
    DOT8(hv4, wdd[16], wdd[17], wdd[18], wdd[19])                            \
    DOT8(hv5, wdd[20], wdd[21], wdd[22], wdd[23])                            \
    DOT8(hv6, wdd[24], wdd[25], wdd[26], wdd[27])                            \
    DOT8(hv7, wdd[28], wdd[29], wdd[30], wdd[31])                            \
    float zv = dv0 + dv1;                                                    \
    zv += __int_as_float(                                                    \
        __builtin_amdgcn_ds_swizzle(__float_as_int(zv), 0x401F));            \
    float z = ((l & 32) ? ac1[0] : ac0[0]) + zv;                             \
    z = fminf(15.0f, fmaxf(-15.0f, z));                                      \
    const float E = __expf(2.0f * z);                                        \
    const float den = fmaf(E, rc, sc);                                       \
    const float num = fmaf(E, p, q);                                         \
    h = num * __builtin_amdgcn_rcpf(den);                                    \
    p = h + dtA;                                                             \
    q = h - dtA;                                                             \
    if (!(l & 16)) hs[WB][o] = (_Float16)h;                                  \
    xpre = xnext;                                                            \
    __syncthreads();                                                         \
  }

  for (int st = 0; st < S_; st += 2) {
    LTC_BODY(0, 1, st)
    LTC_BODY(1, 0, st + 1)
  }
#undef LTC_BODY
#undef DOT8

  // stage final f32 h, then fused output projection
  if (!(l & 16)) hfin[o] = h;
  __syncthreads();

  if (t < O_) {
    float accO = bo[t];
#pragma unroll 8
    for (int hh = 0; hh < H_; ++hh)
      accO = fmaf(hfin[hh], Wo[hh * O_ + t], accO);
    out[b * O_ + t] = accO;
  }
}

// ---------------------------------------------------------------------------
// Fallback (no workspace): proven structure with inline x-proj.
// ---------------------------------------------------------------------------
__global__ __launch_bounds__(1024) void ltc_inline(
    const float* __restrict__ x, const float* __restrict__ W,
    const float* __restrict__ bias, const float* __restrict__ tau,
    const float* __restrict__ A, const float* __restrict__ Wo,
    const float* __restrict__ bo, float* __restrict__ out)
{
  const int b = blockIdx.x;
  const int t = threadIdx.x;
  const int j = t & (H_ - 1);
  const int c = t >> 8;

  float wh[64], wx[32];
#pragma unroll
  for (int kk = 0; kk < 64; ++kk)
    wh[kk] = W[(I_ + c * 64 + kk) * H_ + j];
#pragma unroll
  for (int kk = 0; kk < 32; ++kk)
    wx[kk] = W[(c * 32 + kk) * H_ + j];

  __shared__ __align__(16) float hsf[H_];
  __shared__ __align__(16) float xsf[I_];
  __shared__ float ps[3][H_];

  float Aj = 0.f, itau = 0.f, bj = 0.f;
  if (c == 0) {
    Aj = A[j];
    itau = 1.0f / tau[j];
    bj = bias[j];
    hsf[j] = 0.0f;
  }
  const float4* xrow4 = (const float4*)(x + (size_t)b * S_ * I_);
  if (t < 32) ((float4*)xsf)[t] = xrow4[t];
  __syncthreads();

  for (int step = 0; step < S_; ++step) {
    float4 xnext4 = make_float4(0.f, 0.f, 0.f, 0.f);
    if (t < 32) {
      const int snext = (step + 1 < S_) ? step + 1 : step;
      xnext4 = xrow4[snext * 32 + t];
    }

    float acc = 0.0f;
#pragma unroll
    for (int kk = 0; kk < 64; kk += 4) {
      float4 h4 = *(const float4*)&hsf[c * 64 + kk];
      acc = fmaf(h4.x, wh[kk + 0], acc);
      acc = fmaf(h4.y, wh[kk + 1], acc);
      acc = fmaf(h4.z, wh[kk + 2], acc);
      acc = fmaf(h4.w, wh[kk + 3], acc);
    }
#pragma unroll
    for (int kk = 0; kk < 32; kk += 4) {
      float4 x4 = *(const float4*)&xsf[c * 32 + kk];
      acc = fmaf(x4.x, wx[kk + 0], acc);
      acc = fmaf(x4.y, wx[kk + 1], acc);
      acc = fmaf(x4.z, wx[kk + 2], acc);
      acc = fmaf(x4.w, wx[kk + 3], acc);
    }

    if (c) ps[c - 1][j] = acc;
    __syncthreads();

    if (t < 32) ((float4*)xsf)[t] = xnext4;
    if (c == 0) {
      const float z = acc + ps[0][j] + ps[1][j] + ps[2][j] + bj;
      const float f = tanhf(z);
      const float hj = hsf[j];
      hsf[j] = (hj + DT * f * Aj) / (1.0f + DT * (itau + f));
    }
    __syncthreads();
  }

  if (t < O_) {
    float acc = bo[t];
#pragma unroll 8
    for (int h = 0; h < H_; ++h)
      acc = fmaf(hsf[h], Wo[h * O_ + t], acc);
    out[b * O_ + t] = acc;
  }
}

// ---------------------------------------------------------------------------
extern "C" void kernel_launch(void* const* d_in, const int* in_sizes, int n_in,
                              void* d_out, int out_size, void* d_ws, size_t ws_size,
                              hipStream_t stream) {
  const float* x   = (const float*)d_in[0];
  const float* W   = (const float*)d_in[1];
  const float* b   = (const float*)d_in[2];
  const float* tau = (const float*)d_in[3];
  const float* A   = (const float*)d_in[4];
  const float* Wo  = (const float*)d_in[5];
  const float* bo  = (const float*)d_in[6];
  float* out = (float*)d_out;

  const size_t XP_BYTES = (size_t)B_ * S_ * H_ * sizeof(float);

  if (ws_size >= XP_BYTES) {
    float* xp = (float*)d_ws;
    hipLaunchKernelGGL(xproj_kernel, dim3((B_ * S_) / RPB), dim3(256), 0, stream,
                       x, W, b, xp);
    hipLaunchKernelGGL(ltc_main, dim3(B_), dim3(512), 0, stream,
                       xp, W, tau, A, Wo, bo, out);
  } else {
    hipLaunchKernelGGL(ltc_inline, dim3(B_), dim3(1024), 0, stream,
                       x, W, b, tau, A, Wo, bo, out);
  }
}

// Round 12
// 1782.751 us; speedup vs baseline: 1.2602x; 1.2602x over previous
//
#include <hip/hip_runtime.h>
#include <math.h>

#define DT    0.01f
#define B_    64
#define S_    4096
#define I_    128
#define H_    256
#define O_    128

typedef _Float16 f16x8 __attribute__((ext_vector_type(8)));
typedef float    f32x4 __attribute__((ext_vector_type(4)));

// ---------------------------------------------------------------------------
// Kernel 1: xproj[b,t,j] = b[j] + sum_i x[b,t,i] * W[i,j]   (W rows 0..127)
// ---------------------------------------------------------------------------
#define RPB 64

__global__ __launch_bounds__(256, 2) void xproj_kernel(
    const float* __restrict__ x, const float* __restrict__ W,
    const float* __restrict__ bias, float* __restrict__ xp)
{
  __shared__ __align__(16) float xs[RPB][I_];
  const int j = threadIdx.x;

  float w[I_];
#pragma unroll
  for (int k = 0; k < I_; ++k) w[k] = W[k * H_ + j];
  const float bj = bias[j];

  const size_t row0 = (size_t)blockIdx.x * RPB;

  const float4* src4 = (const float4*)(x + row0 * I_);
  float4* xs4 = (float4*)&xs[0][0];
#pragma unroll
  for (int i = 0; i < (RPB * I_ / 4) / 256; ++i)
    xs4[j + i * 256] = src4[j + i * 256];
  __syncthreads();

  for (int r = 0; r < RPB; r += 4) {
    float a0 = bj, a1 = bj, a2 = bj, a3 = bj;
    const float4* r0 = (const float4*)xs[r + 0];
    const float4* r1 = (const float4*)xs[r + 1];
    const float4* r2 = (const float4*)xs[r + 2];
    const float4* r3 = (const float4*)xs[r + 3];
#pragma unroll
    for (int k4 = 0; k4 < I_ / 4; ++k4) {
      float4 v0 = r0[k4], v1 = r1[k4], v2 = r2[k4], v3 = r3[k4];
      a0 = fmaf(v0.x, w[4*k4+0], a0); a0 = fmaf(v0.y, w[4*k4+1], a0);
      a0 = fmaf(v0.z, w[4*k4+2], a0); a0 = fmaf(v0.w, w[4*k4+3], a0);
      a1 = fmaf(v1.x, w[4*k4+0], a1); a1 = fmaf(v1.y, w[4*k4+1], a1);
      a1 = fmaf(v1.z, w[4*k4+2], a1); a1 = fmaf(v1.w, w[4*k4+3], a1);
      a2 = fmaf(v2.x, w[4*k4+0], a2); a2 = fmaf(v2.y, w[4*k4+1], a2);
      a2 = fmaf(v2.z, w[4*k4+2], a2); a2 = fmaf(v2.w, w[4*k4+3], a2);
      a3 = fmaf(v3.x, w[4*k4+0], a3); a3 = fmaf(v3.y, w[4*k4+1], a3);
      a3 = fmaf(v3.z, w[4*k4+2], a3); a3 = fmaf(v3.w, w[4*k4+3], a3);
    }
    xp[(row0 + r + 0) * H_ + j] = a0;
    xp[(row0 + r + 1) * H_ + j] = a1;
    xp[(row0 + r + 2) * H_ + j] = a2;
    xp[(row0 + r + 3) * H_ + j] = a3;
  }
}

// ---------------------------------------------------------------------------
// Kernel 2: LTC recurrence via MFMA, 512 threads = 8 waves (2/SIMD).
// BEST-MEASURED structure (r6, 1552us) + r10's shorter update algebra.
// Wave wv owns 32 outputs = 2 col-groups x 8 K-tiles = 16 MFMA/wave
// (32/SIMD x 16cy = ~510cy matrix pipe = m06 ceiling; measured saturated).
// Lane l: k-group g=l>>4, col c=l&15, chain s=l>>5 -> o=wv*32+s*16+c.
// C-in seeded with xpre; zero-redundancy update via one cndmask select;
// update algebra: E=exp(2z), h' = (E*p+q)/(E*rc+sc), p=h+dtA, q=h-dtA
// computed off the critical path (r10-verified). Lanes !(l&16) write h'
// (f16) to the other hs buffer; ONE __syncthreads per step.
// Fragment mapping (HW-verified r4-r6,r10): lane element j covers
// k = g*8 + j + kt*32; col = l&15; all A rows identical -> C reg 0 valid.
// Roofline note: step ~910cy = 510 pipe (saturated at ubench 16cy/MFMA,
// tile count K/32 x N/16 = 128/CU forced by the serial recurrence) + ~400
// irreducible exchange chain (ds_read latency + drain + update + barrier).
// Attacks tried and closed: vmcnt-counted barriers (r7), VALU K-offload
// (r8,r11), ILP scaling (r10), wave-count (r5/r6/r10), setprio (r6).
// ---------------------------------------------------------------------------
__global__ __launch_bounds__(512, 2) void ltc_main(
    const float* __restrict__ xp, const float* __restrict__ W,
    const float* __restrict__ tau, const float* __restrict__ A,
    const float* __restrict__ Wo, const float* __restrict__ bo,
    float* __restrict__ out)
{
  const int b  = blockIdx.x;
  const int t  = threadIdx.x;
  const int wv = t >> 6;       // 0..7
  const int l  = t & 63;
  const int g  = l >> 4;       // k-slice group 0..3
  const int c  = l & 15;       // col within 16-group
  const int s  = l >> 5;       // which col-group this lane keeps
  const int o  = wv * 32 + s * 16 + c;  // this lane's output (2 lanes/output)

  // B-fragments: 2 col-groups x 8 K-tiles, register-resident (64 VGPRs)
  f16x8 bw[2][8];
#pragma unroll
  for (int sg = 0; sg < 2; ++sg)
#pragma unroll
    for (int kt = 0; kt < 8; ++kt)
#pragma unroll
      for (int j = 0; j < 8; ++j)
        bw[sg][kt][j] =
            (_Float16)W[(I_ + kt * 32 + g * 8 + j) * H_ + (wv * 32 + sg * 16 + c)];

  __shared__ __align__(16) _Float16 hs[2][H_];
  __shared__ float hfin[H_];

  const float dtA  = DT * A[o];
  const float base = 1.0f + DT * (1.0f / tau[o]);
  const float rc   = base + DT;
  const float sc   = base - DT;

  const float* xprow = xp + (size_t)b * S_ * H_ + o;

  float h = 0.0f, p = dtA, q = -dtA;
  float xpre = xprow[0];
  if (t < H_) hs[0][t] = (_Float16)0.0f;
  __syncthreads();

#define LTC_BODY(RB, WB, STEP)                                               \
  {                                                                          \
    const _Float16* hb = &hs[RB][g * 8];                                     \
    f16x8 a[8];                                                              \
    _Pragma("unroll")                                                        \
    for (int kt = 0; kt < 8; ++kt) a[kt] = *(const f16x8*)(hb + kt * 32);    \
    const int snext = ((STEP) + 1 < S_) ? (STEP) + 1 : (STEP);               \
    const float xnext = xprow[(size_t)snext * H_];                           \
    f32x4 ac00 = {xpre, xpre, xpre, xpre};                                   \
    f32x4 ac01 = {0.f, 0.f, 0.f, 0.f};                                       \
    f32x4 ac10 = {xpre, xpre, xpre, xpre};                                   \
    f32x4 ac11 = {0.f, 0.f, 0.f, 0.f};                                       \
    __builtin_amdgcn_s_setprio(1);                                           \
    _Pragma("unroll")                                                        \
    for (int kt = 0; kt < 4; ++kt) {                                         \
      ac00 = __builtin_amdgcn_mfma_f32_16x16x32_f16(a[kt], bw[0][kt], ac00,  \
                                                    0, 0, 0);                \
      ac10 = __builtin_amdgcn_mfma_f32_16x16x32_f16(a[kt], bw[1][kt], ac10,  \
                                                    0, 0, 0);                \
      ac01 = __builtin_amdgcn_mfma_f32_16x16x32_f16(a[kt + 4], bw[0][kt + 4],\
                                                    ac01, 0, 0, 0);          \
      ac11 = __builtin_amdgcn_mfma_f32_16x16x32_f16(a[kt + 4], bw[1][kt + 4],\
                                                    ac11, 0, 0, 0);          \
    }                                                                        \
    __builtin_amdgcn_s_setprio(0);                                           \
    const float z0 = ac00[0] + ac01[0];                                      \
    const float z1 = ac10[0] + ac11[0];                                      \
    float z = (l & 32) ? z1 : z0;                                            \
    z = fminf(15.0f, fmaxf(-15.0f, z));                                      \
    const float E = __expf(2.0f * z);                                        \
    const float den = fmaf(E, rc, sc);                                       \
    const float num = fmaf(E, p, q);                                         \
    h = num * __builtin_amdgcn_rcpf(den);                                    \
    p = h + dtA;                                                             \
    q = h - dtA;                                                             \
    if (!(l & 16)) hs[WB][o] = (_Float16)h;                                  \
    xpre = xnext;                                                            \
    __syncthreads();                                                         \
  }

  for (int st = 0; st < S_; st += 2) {
    LTC_BODY(0, 1, st)
    LTC_BODY(1, 0, st + 1)
  }
#undef LTC_BODY

  // stage final f32 h, then fused output projection
  if (!(l & 16)) hfin[o] = h;
  __syncthreads();

  if (t < O_) {
    float accO = bo[t];
#pragma unroll 8
    for (int hh = 0; hh < H_; ++hh)
      accO = fmaf(hfin[hh], Wo[hh * O_ + t], accO);
    out[b * O_ + t] = accO;
  }
}

// ---------------------------------------------------------------------------
// Fallback (no workspace): proven structure with inline x-proj.
// ---------------------------------------------------------------------------
__global__ __launch_bounds__(1024) void ltc_inline(
    const float* __restrict__ x, const float* __restrict__ W,
    const float* __restrict__ bias, const float* __restrict__ tau,
    const float* __restrict__ A, const float* __restrict__ Wo,
    const float* __restrict__ bo, float* __restrict__ out)
{
  const int b = blockIdx.x;
  const int t = threadIdx.x;
  const int j = t & (H_ - 1);
  const int c = t >> 8;

  float wh[64], wx[32];
#pragma unroll
  for (int kk = 0; kk < 64; ++kk)
    wh[kk] = W[(I_ + c * 64 + kk) * H_ + j];
#pragma unroll
  for (int kk = 0; kk < 32; ++kk)
    wx[kk] = W[(c * 32 + kk) * H_ + j];

  __shared__ __align__(16) float hsf[H_];
  __shared__ __align__(16) float xsf[I_];
  __shared__ float ps[3][H_];

  float Aj = 0.f, itau = 0.f, bj = 0.f;
  if (c == 0) {
    Aj = A[j];
    itau = 1.0f / tau[j];
    bj = bias[j];
    hsf[j] = 0.0f;
  }
  const float4* xrow4 = (const float4*)(x + (size_t)b * S_ * I_);
  if (t < 32) ((float4*)xsf)[t] = xrow4[t];
  __syncthreads();

  for (int step = 0; step < S_; ++step) {
    float4 xnext4 = make_float4(0.f, 0.f, 0.f, 0.f);
    if (t < 32) {
      const int snext = (step + 1 < S_) ? step + 1 : step;
      xnext4 = xrow4[snext * 32 + t];
    }

    float acc = 0.0f;
#pragma unroll
    for (int kk = 0; kk < 64; kk += 4) {
      float4 h4 = *(const float4*)&hsf[c * 64 + kk];
      acc = fmaf(h4.x, wh[kk + 0], acc);
      acc = fmaf(h4.y, wh[kk + 1], acc);
      acc = fmaf(h4.z, wh[kk + 2], acc);
      acc = fmaf(h4.w, wh[kk + 3], acc);
    }
#pragma unroll
    for (int kk = 0; kk < 32; kk += 4) {
      float4 x4 = *(const float4*)&xsf[c * 32 + kk];
      acc = fmaf(x4.x, wx[kk + 0], acc);
      acc = fmaf(x4.y, wx[kk + 1], acc);
      acc = fmaf(x4.z, wx[kk + 2], acc);
      acc = fmaf(x4.w, wx[kk + 3], acc);
    }

    if (c) ps[c - 1][j] = acc;
    __syncthreads();

    if (t < 32) ((float4*)xsf)[t] = xnext4;
    if (c == 0) {
      const float z = acc + ps[0][j] + ps[1][j] + ps[2][j] + bj;
      const float f = tanhf(z);
      const float hj = hsf[j];
      hsf[j] = (hj + DT * f * Aj) / (1.0f + DT * (itau + f));
    }
    __syncthreads();
  }

  if (t < O_) {
    float acc = bo[t];
#pragma unroll 8
    for (int h = 0; h < H_; ++h)
      acc = fmaf(hsf[h], Wo[h * O_ + t], acc);
    out[b * O_ + t] = acc;
  }
}

// ---------------------------------------------------------------------------
extern "C" void kernel_launch(void* const* d_in, const int* in_sizes, int n_in,
                              void* d_out, int out_size, void* d_ws, size_t ws_size,
                              hipStream_t stream) {
  const float* x   = (const float*)d_in[0];
  const float* W   = (const float*)d_in[1];
  const float* b   = (const float*)d_in[2];
  const float* tau = (const float*)d_in[3];
  const float* A   = (const float*)d_in[4];
  const float* Wo  = (const float*)d_in[5];
  const float* bo  = (const float*)d_in[6];
  float* out = (float*)d_out;

  const size_t XP_BYTES = (size_t)B_ * S_ * H_ * sizeof(float);

  if (ws_size >= XP_BYTES) {
    float* xp = (float*)d_ws;
    hipLaunchKernelGGL(xproj_kernel, dim3((B_ * S_) / RPB), dim3(256), 0, stream,
                       x, W, b, xp);
    hipLaunchKernelGGL(ltc_main, dim3(B_), dim3(512), 0, stream,
                       xp, W, tau, A, Wo, bo, out);
  } else {
    hipLaunchKernelGGL(ltc_inline, dim3(B_), dim3(1024), 0, stream,
                       x, W, b, tau, A, Wo, bo, out);
  }
}